// Round 1
// baseline (1895.163 us; speedup 1.0000x reference)
//
#include <hip/hip_runtime.h>

#define NNODES 100000
#define NEDGES 1600000
#define FDIM 128
#define NGRAPHS 128
#define NLAYERS 4
#define NCLASS 10
#define NB_SCAN ((NNODES + 255) / 256)

// ---------------- graph structure ----------------

__global__ __launch_bounds__(192) void graph_ptr_kernel(const int* __restrict__ batch,
                                                        int* __restrict__ gptr) {
    int g = threadIdx.x;
    if (g > NGRAPHS) return;
    // first index i with batch[i] >= g  (batch is sorted)
    int lo = 0, hi = NNODES;
    while (lo < hi) {
        int mid = (lo + hi) >> 1;
        if (batch[mid] < g) lo = mid + 1; else hi = mid;
    }
    gptr[g] = lo;
}

__global__ __launch_bounds__(256) void deg_kernel(const int* __restrict__ dst,
                                                  int* __restrict__ deg) {
    int e = blockIdx.x * 256 + threadIdx.x;
    if (e < NEDGES) atomicAdd(&deg[dst[e]], 1);
}

__global__ __launch_bounds__(256) void scan_partial(const int* __restrict__ deg,
                                                    int* __restrict__ partial) {
    __shared__ int sd[256];
    int i = blockIdx.x * 256 + threadIdx.x;
    sd[threadIdx.x] = (i < NNODES) ? deg[i] : 0;
    __syncthreads();
    for (int s = 128; s > 0; s >>= 1) {
        if (threadIdx.x < s) sd[threadIdx.x] += sd[threadIdx.x + s];
        __syncthreads();
    }
    if (threadIdx.x == 0) partial[blockIdx.x] = sd[0];
}

__global__ void scan_prefix(int* __restrict__ partial) {
    if (threadIdx.x == 0) {
        int run = 0;
        for (int b = 0; b < NB_SCAN; ++b) { int v = partial[b]; partial[b] = run; run += v; }
    }
}

__global__ __launch_bounds__(256) void scan_final(const int* __restrict__ deg,
                                                  const int* __restrict__ partial,
                                                  int* __restrict__ row_ptr) {
    __shared__ int sd[256];
    int i = blockIdx.x * 256 + threadIdx.x;
    int v = (i < NNODES) ? deg[i] : 0;
    sd[threadIdx.x] = v;
    __syncthreads();
    for (int s = 1; s < 256; s <<= 1) {
        int add = (threadIdx.x >= s) ? sd[threadIdx.x - s] : 0;
        __syncthreads();
        sd[threadIdx.x] += add;
        __syncthreads();
    }
    if (i < NNODES) {
        int excl = sd[threadIdx.x] - v + partial[blockIdx.x];
        row_ptr[i] = excl;
        if (i == NNODES - 1) row_ptr[NNODES] = excl + v;
    }
}

__global__ __launch_bounds__(256) void fill_csr(const int* __restrict__ src,
                                                const int* __restrict__ dst,
                                                const int* __restrict__ row_ptr,
                                                int* __restrict__ cursor,
                                                int* __restrict__ csr) {
    int e = blockIdx.x * 256 + threadIdx.x;
    if (e < NEDGES) {
        int d = dst[e];
        int p = atomicAdd(&cursor[d], 1);
        csr[row_ptr[d] + p] = src[e];
    }
}

// ---------------- aggregation: one wave per node ----------------

__global__ __launch_bounds__(256) void agg_kernel(const float* __restrict__ h,
                                                  const int* __restrict__ row_ptr,
                                                  const int* __restrict__ csr,
                                                  float* __restrict__ agg) {
    int wave = threadIdx.x >> 6;
    int lane = threadIdx.x & 63;
    int node = (blockIdx.x << 2) + wave;
    if (node >= NNODES) return;
    int e0 = row_ptr[node], e1 = row_ptr[node + 1];
    float ax = 0.f, ay = 0.f;
    int e = e0;
    for (; e + 2 <= e1; e += 2) {
        int s0 = csr[e], s1 = csr[e + 1];
        float2 v0 = ((const float2*)(h + (size_t)s0 * FDIM))[lane];
        float2 v1 = ((const float2*)(h + (size_t)s1 * FDIM))[lane];
        ax += v0.x; ay += v0.y;
        ax += v1.x; ay += v1.y;
    }
    if (e < e1) {
        int s0 = csr[e];
        float2 v0 = ((const float2*)(h + (size_t)s0 * FDIM))[lane];
        ax += v0.x; ay += v0.y;
    }
    float2 o; o.x = ax; o.y = ay;
    ((float2*)(agg + (size_t)node * FDIM))[lane] = o;
}

// ---------------- fused GraphConv GEMM: relu([agg|h] @ [Wrel;Wroot] + b) ----------------
// tile 128 rows x 128 cols, K=256 in chunks of 16, 256 threads, 8x8 micro-tile

__global__ __launch_bounds__(256) void gemm_fused(const float* __restrict__ agg,
                                                  const float* __restrict__ hin,
                                                  const float* __restrict__ Wrel,
                                                  const float* __restrict__ Wroot,
                                                  const float* __restrict__ bias,
                                                  float* __restrict__ hout) {
    __shared__ float Xs[16][128];   // k-major
    __shared__ float Ws[16][128];
    const int t = threadIdx.x;
    const int row0 = blockIdx.x * 128;
    const int tr = t >> 4;          // 0..15 row group
    const int tc = t & 15;          // 0..15 col group

    float acc[8][8];
#pragma unroll
    for (int r = 0; r < 8; ++r)
#pragma unroll
        for (int c = 0; c < 8; ++c) acc[r][c] = 0.f;

    const int lrow = t >> 1;            // X loader: row 0..127
    const int lko  = (t & 1) * 8;       // k offset within chunk
    const int wkk  = t >> 4;            // W loader: k row 0..15
    const int wj   = (t & 15) * 8;      // col offset

    for (int kb = 0; kb < 256; kb += 16) {
        {   // X chunk (transposed into LDS)
            int grow = row0 + lrow;
            int gk = kb + lko;
            float4 v0 = make_float4(0.f, 0.f, 0.f, 0.f), v1 = v0;
            if (grow < NNODES) {
                const float* s = (gk < 128) ? (agg + (size_t)grow * 128 + gk)
                                            : (hin + (size_t)grow * 128 + (gk - 128));
                v0 = *(const float4*)(s);
                v1 = *(const float4*)(s + 4);
            }
            Xs[lko + 0][lrow] = v0.x; Xs[lko + 1][lrow] = v0.y;
            Xs[lko + 2][lrow] = v0.z; Xs[lko + 3][lrow] = v0.w;
            Xs[lko + 4][lrow] = v1.x; Xs[lko + 5][lrow] = v1.y;
            Xs[lko + 6][lrow] = v1.z; Xs[lko + 7][lrow] = v1.w;
        }
        {   // W chunk
            int gk = kb + wkk;
            const float* s = (gk < 128) ? (Wrel + (size_t)gk * 128 + wj)
                                        : (Wroot + (size_t)(gk - 128) * 128 + wj);
            *(float4*)&Ws[wkk][wj]     = *(const float4*)(s);
            *(float4*)&Ws[wkk][wj + 4] = *(const float4*)(s + 4);
        }
        __syncthreads();
#pragma unroll
        for (int kk = 0; kk < 16; ++kk) {
            float4 a0 = *(const float4*)&Xs[kk][tr * 8];
            float4 a1 = *(const float4*)&Xs[kk][tr * 8 + 4];
            float4 b0 = *(const float4*)&Ws[kk][tc * 8];
            float4 b1 = *(const float4*)&Ws[kk][tc * 8 + 4];
            float a[8] = {a0.x, a0.y, a0.z, a0.w, a1.x, a1.y, a1.z, a1.w};
            float b[8] = {b0.x, b0.y, b0.z, b0.w, b1.x, b1.y, b1.z, b1.w};
#pragma unroll
            for (int r = 0; r < 8; ++r)
#pragma unroll
                for (int c = 0; c < 8; ++c)
                    acc[r][c] = fmaf(a[r], b[c], acc[r][c]);
        }
        __syncthreads();
    }
    float bb[8];
#pragma unroll
    for (int c = 0; c < 8; ++c) bb[c] = bias[tc * 8 + c];
#pragma unroll
    for (int r = 0; r < 8; ++r) {
        int row = row0 + tr * 8 + r;
        if (row < NNODES) {
            float4 o0, o1;
            o0.x = fmaxf(acc[r][0] + bb[0], 0.f);
            o0.y = fmaxf(acc[r][1] + bb[1], 0.f);
            o0.z = fmaxf(acc[r][2] + bb[2], 0.f);
            o0.w = fmaxf(acc[r][3] + bb[3], 0.f);
            o1.x = fmaxf(acc[r][4] + bb[4], 0.f);
            o1.y = fmaxf(acc[r][5] + bb[5], 0.f);
            o1.z = fmaxf(acc[r][6] + bb[6], 0.f);
            o1.w = fmaxf(acc[r][7] + bb[7], 0.f);
            float* dsts = hout + (size_t)row * 128 + tc * 8;
            *(float4*)dsts = o0;
            *(float4*)(dsts + 4) = o1;
        }
    }
}

// ---------------- mean pool per graph (batch is sorted -> contiguous ranges) ----------------

__global__ __launch_bounds__(128) void pool_kernel(const float* __restrict__ h,
                                                   const int* __restrict__ gptr,
                                                   float* __restrict__ z, int layer) {
    int g = blockIdx.x, f = threadIdx.x;
    int n0 = gptr[g], n1 = gptr[g + 1];
    float s = 0.f;
    for (int n = n0; n < n1; ++n) s += h[(size_t)n * FDIM + f];
    int cnt = n1 - n0; if (cnt < 1) cnt = 1;
    z[(size_t)g * (NLAYERS * FDIM) + layer * FDIM + f] = s / (float)cnt;
}

// ---------------- final MLP ----------------

__global__ __launch_bounds__(128) void mlp1(const float* __restrict__ z,
                                            const float* __restrict__ Wl1,
                                            const float* __restrict__ bl1,
                                            float* __restrict__ z2) {
    int g = blockIdx.x, j = threadIdx.x;
    __shared__ float zs[NLAYERS * FDIM];
    for (int k = j; k < NLAYERS * FDIM; k += 128) zs[k] = z[(size_t)g * (NLAYERS * FDIM) + k];
    __syncthreads();
    float s = bl1[j];
    for (int k = 0; k < NLAYERS * FDIM; ++k) s = fmaf(zs[k], Wl1[(size_t)k * FDIM + j], s);
    z2[(size_t)g * FDIM + j] = fmaxf(s, 0.f);
}

__global__ __launch_bounds__(128) void mlp2(const float* __restrict__ z2,
                                            const float* __restrict__ Wl2,
                                            const float* __restrict__ bl2,
                                            float* __restrict__ out) {
    int g = blockIdx.x, c = threadIdx.x;
    __shared__ float zs[FDIM];
    if (threadIdx.x < FDIM) zs[threadIdx.x] = z2[(size_t)g * FDIM + threadIdx.x];
    __syncthreads();
    if (c < NCLASS) {
        float s = bl2[c];
        for (int k = 0; k < FDIM; ++k) s = fmaf(zs[k], Wl2[(size_t)k * NCLASS + c], s);
        out[(size_t)g * NCLASS + c] = s;
    }
}

// ---------------- launch ----------------

extern "C" void kernel_launch(void* const* d_in, const int* in_sizes, int n_in,
                              void* d_out, int out_size, void* d_ws, size_t ws_size,
                              hipStream_t stream) {
    const float* x       = (const float*)d_in[0];
    const int*   ei      = (const int*)d_in[1];
    const int*   batch   = (const int*)d_in[2];
    const float* W1_rel  = (const float*)d_in[3];
    const float* b1_rel  = (const float*)d_in[4];
    const float* W1_root = (const float*)d_in[5];
    const float* Wc_rel  = (const float*)d_in[6];
    const float* bc_rel  = (const float*)d_in[7];
    const float* Wc_root = (const float*)d_in[8];
    const float* Wl1     = (const float*)d_in[9];
    const float* bl1     = (const float*)d_in[10];
    const float* Wl2     = (const float*)d_in[11];
    const float* bl2     = (const float*)d_in[12];
    float* out = (float*)d_out;

    const int* srcv = ei;            // edge_index[0]
    const int* dstv = ei + NEDGES;   // edge_index[1]

    char* ws = (char*)d_ws;
    size_t off = 0;
    auto alloc = [&](size_t bytes) -> void* {
        void* p = ws + off;
        off = (off + bytes + 255) & ~(size_t)255;
        return p;
    };
    float* hA     = (float*)alloc((size_t)NNODES * FDIM * 4);
    float* hB     = (float*)alloc((size_t)NNODES * FDIM * 4);
    float* agg    = (float*)alloc((size_t)NNODES * FDIM * 4);
    int* csr      = (int*)alloc((size_t)NEDGES * 4);
    int* row_ptr  = (int*)alloc((size_t)(NNODES + 1) * 4);
    int* degcur   = (int*)alloc((size_t)NNODES * 2 * 4);
    int* deg = degcur; int* cursor = degcur + NNODES;
    int* partial  = (int*)alloc(4096);
    int* gptr     = (int*)alloc(1024);
    float* z      = (float*)alloc((size_t)NGRAPHS * NLAYERS * FDIM * 4);
    float* z2     = (float*)alloc((size_t)NGRAPHS * FDIM * 4);
    (void)ws_size; (void)in_sizes; (void)n_in; (void)out_size;

    hipMemsetAsync(degcur, 0, (size_t)NNODES * 2 * 4, stream);
    graph_ptr_kernel<<<1, 192, 0, stream>>>(batch, gptr);
    deg_kernel<<<(NEDGES + 255) / 256, 256, 0, stream>>>(dstv, deg);
    scan_partial<<<NB_SCAN, 256, 0, stream>>>(deg, partial);
    scan_prefix<<<1, 64, 0, stream>>>(partial);
    scan_final<<<NB_SCAN, 256, 0, stream>>>(deg, partial, row_ptr);
    fill_csr<<<(NEDGES + 255) / 256, 256, 0, stream>>>(srcv, dstv, row_ptr, cursor, csr);

    const float* hin = x;
    for (int l = 0; l < NLAYERS; ++l) {
        float* hout = (l & 1) ? hB : hA;
        const float* Wr = (l == 0) ? W1_rel  : Wc_rel  + (size_t)(l - 1) * FDIM * FDIM;
        const float* Wt = (l == 0) ? W1_root : Wc_root + (size_t)(l - 1) * FDIM * FDIM;
        const float* bb = (l == 0) ? b1_rel  : bc_rel  + (size_t)(l - 1) * FDIM;
        agg_kernel<<<(NNODES + 3) / 4, 256, 0, stream>>>(hin, row_ptr, csr, agg);
        gemm_fused<<<(NNODES + 127) / 128, 256, 0, stream>>>(agg, hin, Wr, Wt, bb, hout);
        pool_kernel<<<NGRAPHS, 128, 0, stream>>>(hout, gptr, z, l);
        hin = hout;
    }
    mlp1<<<NGRAPHS, 128, 0, stream>>>(z, Wl1, bl1, z2);
    mlp2<<<NGRAPHS, 128, 0, stream>>>(z2, Wl2, bl2, out);
}

// Round 2
// 1243.105 us; speedup vs baseline: 1.5245x; 1.5245x over previous
//
#include <hip/hip_runtime.h>

#define NNODES 100000
#define NEDGES 1600000
#define FDIM 128
#define NGRAPHS 128
#define NLAYERS 4
#define NCLASS 10
#define NB_SCAN ((NNODES + 255) / 256)
#define POOL_NPB 128

// ---------------- graph structure ----------------

__global__ __launch_bounds__(192) void graph_ptr_kernel(const int* __restrict__ batch,
                                                        int* __restrict__ gptr) {
    int g = threadIdx.x;
    if (g > NGRAPHS) return;
    // first index i with batch[i] >= g  (batch is sorted)
    int lo = 0, hi = NNODES;
    while (lo < hi) {
        int mid = (lo + hi) >> 1;
        if (batch[mid] < g) lo = mid + 1; else hi = mid;
    }
    gptr[g] = lo;
}

__global__ __launch_bounds__(256) void deg_kernel(const int* __restrict__ dst,
                                                  int* __restrict__ deg) {
    int e = blockIdx.x * 256 + threadIdx.x;
    if (e < NEDGES) atomicAdd(&deg[dst[e]], 1);
}

__global__ __launch_bounds__(256) void scan_partial(const int* __restrict__ deg,
                                                    int* __restrict__ partial) {
    __shared__ int sd[256];
    int i = blockIdx.x * 256 + threadIdx.x;
    sd[threadIdx.x] = (i < NNODES) ? deg[i] : 0;
    __syncthreads();
    for (int s = 128; s > 0; s >>= 1) {
        if (threadIdx.x < s) sd[threadIdx.x] += sd[threadIdx.x + s];
        __syncthreads();
    }
    if (threadIdx.x == 0) partial[blockIdx.x] = sd[0];
}

__global__ void scan_prefix(int* __restrict__ partial) {
    if (threadIdx.x == 0) {
        int run = 0;
        for (int b = 0; b < NB_SCAN; ++b) { int v = partial[b]; partial[b] = run; run += v; }
    }
}

__global__ __launch_bounds__(256) void scan_final(const int* __restrict__ deg,
                                                  const int* __restrict__ partial,
                                                  int* __restrict__ row_ptr) {
    __shared__ int sd[256];
    int i = blockIdx.x * 256 + threadIdx.x;
    int v = (i < NNODES) ? deg[i] : 0;
    sd[threadIdx.x] = v;
    __syncthreads();
    for (int s = 1; s < 256; s <<= 1) {
        int add = (threadIdx.x >= s) ? sd[threadIdx.x - s] : 0;
        __syncthreads();
        sd[threadIdx.x] += add;
        __syncthreads();
    }
    if (i < NNODES) {
        int excl = sd[threadIdx.x] - v + partial[blockIdx.x];
        row_ptr[i] = excl;
        if (i == NNODES - 1) row_ptr[NNODES] = excl + v;
    }
}

__global__ __launch_bounds__(256) void fill_csr(const int* __restrict__ src,
                                                const int* __restrict__ dst,
                                                const int* __restrict__ row_ptr,
                                                int* __restrict__ cursor,
                                                int* __restrict__ csr) {
    int e = blockIdx.x * 256 + threadIdx.x;
    if (e < NEDGES) {
        int d = dst[e];
        int p = atomicAdd(&cursor[d], 1);
        csr[row_ptr[d] + p] = src[e];
    }
}

// ---------------- aggregation: one wave per node ----------------

__global__ __launch_bounds__(256) void agg_kernel(const float* __restrict__ h,
                                                  const int* __restrict__ row_ptr,
                                                  const int* __restrict__ csr,
                                                  float* __restrict__ agg) {
    int wave = threadIdx.x >> 6;
    int lane = threadIdx.x & 63;
    int node = (blockIdx.x << 2) + wave;
    if (node >= NNODES) return;
    int e0 = row_ptr[node], e1 = row_ptr[node + 1];
    float ax = 0.f, ay = 0.f;
    int e = e0;
    for (; e + 2 <= e1; e += 2) {
        int s0 = csr[e], s1 = csr[e + 1];
        float2 v0 = ((const float2*)(h + (size_t)s0 * FDIM))[lane];
        float2 v1 = ((const float2*)(h + (size_t)s1 * FDIM))[lane];
        ax += v0.x; ay += v0.y;
        ax += v1.x; ay += v1.y;
    }
    if (e < e1) {
        int s0 = csr[e];
        float2 v0 = ((const float2*)(h + (size_t)s0 * FDIM))[lane];
        ax += v0.x; ay += v0.y;
    }
    float2 o; o.x = ax; o.y = ay;
    ((float2*)(agg + (size_t)node * FDIM))[lane] = o;
}

// ---------------- fused GraphConv GEMM: relu([agg|h] @ [Wrel;Wroot] + b) ----------------

__global__ __launch_bounds__(256) void gemm_fused(const float* __restrict__ agg,
                                                  const float* __restrict__ hin,
                                                  const float* __restrict__ Wrel,
                                                  const float* __restrict__ Wroot,
                                                  const float* __restrict__ bias,
                                                  float* __restrict__ hout) {
    __shared__ float Xs[16][128];   // k-major
    __shared__ float Ws[16][128];
    const int t = threadIdx.x;
    const int row0 = blockIdx.x * 128;
    const int tr = t >> 4;          // 0..15 row group
    const int tc = t & 15;          // 0..15 col group

    float acc[8][8];
#pragma unroll
    for (int r = 0; r < 8; ++r)
#pragma unroll
        for (int c = 0; c < 8; ++c) acc[r][c] = 0.f;

    const int lrow = t >> 1;            // X loader: row 0..127
    const int lko  = (t & 1) * 8;       // k offset within chunk
    const int wkk  = t >> 4;            // W loader: k row 0..15
    const int wj   = (t & 15) * 8;      // col offset

    for (int kb = 0; kb < 256; kb += 16) {
        {   // X chunk (transposed into LDS)
            int grow = row0 + lrow;
            int gk = kb + lko;
            float4 v0 = make_float4(0.f, 0.f, 0.f, 0.f), v1 = v0;
            if (grow < NNODES) {
                const float* s = (gk < 128) ? (agg + (size_t)grow * 128 + gk)
                                            : (hin + (size_t)grow * 128 + (gk - 128));
                v0 = *(const float4*)(s);
                v1 = *(const float4*)(s + 4);
            }
            Xs[lko + 0][lrow] = v0.x; Xs[lko + 1][lrow] = v0.y;
            Xs[lko + 2][lrow] = v0.z; Xs[lko + 3][lrow] = v0.w;
            Xs[lko + 4][lrow] = v1.x; Xs[lko + 5][lrow] = v1.y;
            Xs[lko + 6][lrow] = v1.z; Xs[lko + 7][lrow] = v1.w;
        }
        {   // W chunk
            int gk = kb + wkk;
            const float* s = (gk < 128) ? (Wrel + (size_t)gk * 128 + wj)
                                        : (Wroot + (size_t)(gk - 128) * 128 + wj);
            *(float4*)&Ws[wkk][wj]     = *(const float4*)(s);
            *(float4*)&Ws[wkk][wj + 4] = *(const float4*)(s + 4);
        }
        __syncthreads();
#pragma unroll
        for (int kk = 0; kk < 16; ++kk) {
            float4 a0 = *(const float4*)&Xs[kk][tr * 8];
            float4 a1 = *(const float4*)&Xs[kk][tr * 8 + 4];
            float4 b0 = *(const float4*)&Ws[kk][tc * 8];
            float4 b1 = *(const float4*)&Ws[kk][tc * 8 + 4];
            float a[8] = {a0.x, a0.y, a0.z, a0.w, a1.x, a1.y, a1.z, a1.w};
            float b[8] = {b0.x, b0.y, b0.z, b0.w, b1.x, b1.y, b1.z, b1.w};
#pragma unroll
            for (int r = 0; r < 8; ++r)
#pragma unroll
                for (int c = 0; c < 8; ++c)
                    acc[r][c] = fmaf(a[r], b[c], acc[r][c]);
        }
        __syncthreads();
    }
    float bb[8];
#pragma unroll
    for (int c = 0; c < 8; ++c) bb[c] = bias[tc * 8 + c];
#pragma unroll
    for (int r = 0; r < 8; ++r) {
        int row = row0 + tr * 8 + r;
        if (row < NNODES) {
            float4 o0, o1;
            o0.x = fmaxf(acc[r][0] + bb[0], 0.f);
            o0.y = fmaxf(acc[r][1] + bb[1], 0.f);
            o0.z = fmaxf(acc[r][2] + bb[2], 0.f);
            o0.w = fmaxf(acc[r][3] + bb[3], 0.f);
            o1.x = fmaxf(acc[r][4] + bb[4], 0.f);
            o1.y = fmaxf(acc[r][5] + bb[5], 0.f);
            o1.z = fmaxf(acc[r][6] + bb[6], 0.f);
            o1.w = fmaxf(acc[r][7] + bb[7], 0.f);
            float* dsts = hout + (size_t)row * 128 + tc * 8;
            *(float4*)dsts = o0;
            *(float4*)(dsts + 4) = o1;
        }
    }
}

// ---------------- node-parallel mean pool (sums; /count folded into mlp1) ----------------
// batch is sorted: run-length accumulate, atomicAdd only at graph boundaries.

__global__ __launch_bounds__(128) void pool_fast(const float* __restrict__ h,
                                                 const int* __restrict__ batch,
                                                 float* __restrict__ z, int layer) {
    const int f = threadIdx.x;
    const int n0 = blockIdx.x * POOL_NPB;
    int n1 = n0 + POOL_NPB; if (n1 > NNODES) n1 = NNODES;
    __shared__ int bsh[POOL_NPB];
    for (int n = n0 + f; n < n1; n += 128) bsh[n - n0] = batch[n];
    __syncthreads();
    float s = 0.f;
    int g = bsh[0];
    for (int n = n0; n < n1; ++n) {
        int gn = bsh[n - n0];
        if (gn != g) {
            atomicAdd(&z[(size_t)g * (NLAYERS * FDIM) + layer * FDIM + f], s);
            s = 0.f; g = gn;
        }
        s += h[(size_t)n * FDIM + f];
    }
    atomicAdd(&z[(size_t)g * (NLAYERS * FDIM) + layer * FDIM + f], s);
}

// ---------------- final MLP (mean normalization folded into z load) ----------------

__global__ __launch_bounds__(128) void mlp1(const float* __restrict__ z,
                                            const int* __restrict__ gptr,
                                            const float* __restrict__ Wl1,
                                            const float* __restrict__ bl1,
                                            float* __restrict__ z2) {
    int g = blockIdx.x, j = threadIdx.x;
    __shared__ float zs[NLAYERS * FDIM];
    int cnt = gptr[g + 1] - gptr[g]; if (cnt < 1) cnt = 1;
    float invc = 1.0f / (float)cnt;
    for (int k = j; k < NLAYERS * FDIM; k += 128)
        zs[k] = z[(size_t)g * (NLAYERS * FDIM) + k] * invc;
    __syncthreads();
    float s = bl1[j];
    for (int k = 0; k < NLAYERS * FDIM; ++k) s = fmaf(zs[k], Wl1[(size_t)k * FDIM + j], s);
    z2[(size_t)g * FDIM + j] = fmaxf(s, 0.f);
}

__global__ __launch_bounds__(128) void mlp2(const float* __restrict__ z2,
                                            const float* __restrict__ Wl2,
                                            const float* __restrict__ bl2,
                                            float* __restrict__ out) {
    int g = blockIdx.x, c = threadIdx.x;
    __shared__ float zs[FDIM];
    if (threadIdx.x < FDIM) zs[threadIdx.x] = z2[(size_t)g * FDIM + threadIdx.x];
    __syncthreads();
    if (c < NCLASS) {
        float s = bl2[c];
        for (int k = 0; k < FDIM; ++k) s = fmaf(zs[k], Wl2[(size_t)k * NCLASS + c], s);
        out[(size_t)g * NCLASS + c] = s;
    }
}

// ---------------- launch ----------------

extern "C" void kernel_launch(void* const* d_in, const int* in_sizes, int n_in,
                              void* d_out, int out_size, void* d_ws, size_t ws_size,
                              hipStream_t stream) {
    const float* x       = (const float*)d_in[0];
    const int*   ei      = (const int*)d_in[1];
    const int*   batch   = (const int*)d_in[2];
    const float* W1_rel  = (const float*)d_in[3];
    const float* b1_rel  = (const float*)d_in[4];
    const float* W1_root = (const float*)d_in[5];
    const float* Wc_rel  = (const float*)d_in[6];
    const float* bc_rel  = (const float*)d_in[7];
    const float* Wc_root = (const float*)d_in[8];
    const float* Wl1     = (const float*)d_in[9];
    const float* bl1     = (const float*)d_in[10];
    const float* Wl2     = (const float*)d_in[11];
    const float* bl2     = (const float*)d_in[12];
    float* out = (float*)d_out;

    const int* srcv = ei;            // edge_index[0]
    const int* dstv = ei + NEDGES;   // edge_index[1]

    char* ws = (char*)d_ws;
    size_t off = 0;
    auto alloc = [&](size_t bytes) -> void* {
        void* p = ws + off;
        off = (off + bytes + 255) & ~(size_t)255;
        return p;
    };
    float* hA     = (float*)alloc((size_t)NNODES * FDIM * 4);
    float* hB     = (float*)alloc((size_t)NNODES * FDIM * 4);
    float* agg    = (float*)alloc((size_t)NNODES * FDIM * 4);
    int* csr      = (int*)alloc((size_t)NEDGES * 4);
    int* row_ptr  = (int*)alloc((size_t)(NNODES + 1) * 4);
    int* degcur   = (int*)alloc((size_t)NNODES * 2 * 4);
    int* deg = degcur; int* cursor = degcur + NNODES;
    int* partial  = (int*)alloc(4096);
    int* gptr     = (int*)alloc(1024);
    float* z      = (float*)alloc((size_t)NGRAPHS * NLAYERS * FDIM * 4);
    float* z2     = (float*)alloc((size_t)NGRAPHS * FDIM * 4);
    (void)ws_size; (void)in_sizes; (void)n_in; (void)out_size;

    hipMemsetAsync(degcur, 0, (size_t)NNODES * 2 * 4, stream);
    hipMemsetAsync(z, 0, (size_t)NGRAPHS * NLAYERS * FDIM * 4, stream);
    graph_ptr_kernel<<<1, 192, 0, stream>>>(batch, gptr);
    deg_kernel<<<(NEDGES + 255) / 256, 256, 0, stream>>>(dstv, deg);
    scan_partial<<<NB_SCAN, 256, 0, stream>>>(deg, partial);
    scan_prefix<<<1, 64, 0, stream>>>(partial);
    scan_final<<<NB_SCAN, 256, 0, stream>>>(deg, partial, row_ptr);
    fill_csr<<<(NEDGES + 255) / 256, 256, 0, stream>>>(srcv, dstv, row_ptr, cursor, csr);

    const int pool_nb = (NNODES + POOL_NPB - 1) / POOL_NPB;
    const float* hin = x;
    for (int l = 0; l < NLAYERS; ++l) {
        float* hout = (l & 1) ? hB : hA;
        const float* Wr = (l == 0) ? W1_rel  : Wc_rel  + (size_t)(l - 1) * FDIM * FDIM;
        const float* Wt = (l == 0) ? W1_root : Wc_root + (size_t)(l - 1) * FDIM * FDIM;
        const float* bb = (l == 0) ? b1_rel  : bc_rel  + (size_t)(l - 1) * FDIM;
        agg_kernel<<<(NNODES + 3) / 4, 256, 0, stream>>>(hin, row_ptr, csr, agg);
        gemm_fused<<<(NNODES + 127) / 128, 256, 0, stream>>>(agg, hin, Wr, Wt, bb, hout);
        pool_fast<<<pool_nb, 128, 0, stream>>>(hout, batch, z, l);
        hin = hout;
    }
    mlp1<<<NGRAPHS, 128, 0, stream>>>(z, gptr, Wl1, bl1, z2);
    mlp2<<<NGRAPHS, 128, 0, stream>>>(z2, Wl2, bl2, out);
}

// Round 3
// 844.122 us; speedup vs baseline: 2.2451x; 1.4727x over previous
//
#include <hip/hip_runtime.h>

#define NNODES 100000
#define NEDGES 1600000
#define FDIM 128
#define NGRAPHS 128
#define NLAYERS 4
#define NCLASS 10
#define NB_SCAN ((NNODES + 255) / 256)
#define POOL_NPB 128
#define LDA 40      // padded LDS row stride (elems): 80 B = 5*16 B -> 2-way bank alias (free)
#define LDC 136     // epilogue LDS row stride (elems): 272 B, 16B-aligned rows

typedef __attribute__((ext_vector_type(8))) short bf16x8;
typedef __attribute__((ext_vector_type(4))) float f32x4;
typedef unsigned short u16;
typedef unsigned int u32;

__device__ __forceinline__ u16 f2bf(float f) {
    u32 u = __float_as_uint(f);
    u += 0x7fffu + ((u >> 16) & 1u);   // round-to-nearest-even
    return (u16)(u >> 16);
}
__device__ __forceinline__ float bf_lo(u32 u) { return __uint_as_float(u << 16); }
__device__ __forceinline__ float bf_hi(u32 u) { return __uint_as_float(u & 0xffff0000u); }
__device__ __forceinline__ u32 pack_bf(float a, float b) {
    return (u32)f2bf(a) | ((u32)f2bf(b) << 16);
}

// ---------------- dtype conversion ----------------

__global__ __launch_bounds__(256) void conv_x(const float* __restrict__ x,
                                              u16* __restrict__ xb) {
    int i = (blockIdx.x * 256 + threadIdx.x) * 4;
    if (i < NNODES * FDIM) {
        float4 v = *(const float4*)(x + i);
        u32 p0 = pack_bf(v.x, v.y), p1 = pack_bf(v.z, v.w);
        *(u32*)(xb + i) = p0;
        *(u32*)(xb + i + 2) = p1;
    }
}

// Wcat[l][n][k]: k<128 -> Wrel[k][n], k>=128 -> Wroot[k-128][n]  (transposed, concat)
__global__ __launch_bounds__(256) void conv_w(const float* __restrict__ W1_rel,
                                              const float* __restrict__ W1_root,
                                              const float* __restrict__ Wc_rel,
                                              const float* __restrict__ Wc_root,
                                              u16* __restrict__ Wcat) {
    int idx = blockIdx.x * 256 + threadIdx.x;      // 4*256*128 = 131072
    if (idx >= NLAYERS * 256 * FDIM) return;
    int n = idx & 127;
    int k = (idx >> 7) & 255;
    int l = idx >> 15;
    const float* Wr = (l == 0) ? W1_rel  : Wc_rel  + (size_t)(l - 1) * FDIM * FDIM;
    const float* Wt = (l == 0) ? W1_root : Wc_root + (size_t)(l - 1) * FDIM * FDIM;
    float v = (k < 128) ? Wr[(size_t)k * FDIM + n] : Wt[(size_t)(k - 128) * FDIM + n];
    Wcat[(size_t)l * 32768 + (size_t)n * 256 + k] = f2bf(v);
}

// ---------------- graph structure ----------------

__global__ __launch_bounds__(192) void graph_ptr_kernel(const int* __restrict__ batch,
                                                        int* __restrict__ gptr) {
    int g = threadIdx.x;
    if (g > NGRAPHS) return;
    int lo = 0, hi = NNODES;
    while (lo < hi) {
        int mid = (lo + hi) >> 1;
        if (batch[mid] < g) lo = mid + 1; else hi = mid;
    }
    gptr[g] = lo;
}

__global__ __launch_bounds__(256) void deg_kernel(const int* __restrict__ dst,
                                                  int* __restrict__ deg) {
    int e = blockIdx.x * 256 + threadIdx.x;
    if (e < NEDGES) atomicAdd(&deg[dst[e]], 1);
}

__global__ __launch_bounds__(256) void scan_partial(const int* __restrict__ deg,
                                                    int* __restrict__ partial) {
    __shared__ int sd[256];
    int i = blockIdx.x * 256 + threadIdx.x;
    sd[threadIdx.x] = (i < NNODES) ? deg[i] : 0;
    __syncthreads();
    for (int s = 128; s > 0; s >>= 1) {
        if (threadIdx.x < s) sd[threadIdx.x] += sd[threadIdx.x + s];
        __syncthreads();
    }
    if (threadIdx.x == 0) partial[blockIdx.x] = sd[0];
}

__global__ void scan_prefix(int* __restrict__ partial) {
    if (threadIdx.x == 0) {
        int run = 0;
        for (int b = 0; b < NB_SCAN; ++b) { int v = partial[b]; partial[b] = run; run += v; }
    }
}

__global__ __launch_bounds__(256) void scan_final(const int* __restrict__ deg,
                                                  const int* __restrict__ partial,
                                                  int* __restrict__ row_ptr) {
    __shared__ int sd[256];
    int i = blockIdx.x * 256 + threadIdx.x;
    int v = (i < NNODES) ? deg[i] : 0;
    sd[threadIdx.x] = v;
    __syncthreads();
    for (int s = 1; s < 256; s <<= 1) {
        int add = (threadIdx.x >= s) ? sd[threadIdx.x - s] : 0;
        __syncthreads();
        sd[threadIdx.x] += add;
        __syncthreads();
    }
    if (i < NNODES) {
        int excl = sd[threadIdx.x] - v + partial[blockIdx.x];
        row_ptr[i] = excl;
        if (i == NNODES - 1) row_ptr[NNODES] = excl + v;
    }
}

__global__ __launch_bounds__(256) void fill_csr(const int* __restrict__ src,
                                                const int* __restrict__ dst,
                                                const int* __restrict__ row_ptr,
                                                int* __restrict__ cursor,
                                                int* __restrict__ csr) {
    int e = blockIdx.x * 256 + threadIdx.x;
    if (e < NEDGES) {
        int d = dst[e];
        int p = atomicAdd(&cursor[d], 1);
        csr[row_ptr[d] + p] = src[e];
    }
}

// ---------------- aggregation (bf16 gather, fp32 accum): one wave per node ----------------

__global__ __launch_bounds__(256) void agg_bf(const u16* __restrict__ h,
                                              const int* __restrict__ row_ptr,
                                              const int* __restrict__ csr,
                                              u16* __restrict__ agg) {
    int wave = threadIdx.x >> 6;
    int lane = threadIdx.x & 63;
    int node = (blockIdx.x << 2) + wave;
    if (node >= NNODES) return;
    int e0 = row_ptr[node], e1 = row_ptr[node + 1];
    float ax = 0.f, ay = 0.f;
    int e = e0;
    for (; e + 2 <= e1; e += 2) {
        int s0 = csr[e], s1 = csr[e + 1];
        u32 v0 = ((const u32*)(h + (size_t)s0 * FDIM))[lane];
        u32 v1 = ((const u32*)(h + (size_t)s1 * FDIM))[lane];
        ax += bf_lo(v0); ay += bf_hi(v0);
        ax += bf_lo(v1); ay += bf_hi(v1);
    }
    if (e < e1) {
        int s0 = csr[e];
        u32 v0 = ((const u32*)(h + (size_t)s0 * FDIM))[lane];
        ax += bf_lo(v0); ay += bf_hi(v0);
    }
    ((u32*)(agg + (size_t)node * FDIM))[lane] = pack_bf(ax, ay);
}

// ---------------- MFMA GEMM: relu([agg|h] @ Wcat^T + b), bf16 in/out, fp32 accum ----------
// 128x128 tile, 4 waves (2x2), K=256 in 8 steps of 32, mfma_f32_16x16x32_bf16

__global__ __launch_bounds__(256) void gemm_mfma(const u16* __restrict__ aggb,
                                                 const u16* __restrict__ hinb,
                                                 const u16* __restrict__ Wl,   // [128 n][256 k]
                                                 const float* __restrict__ bias,
                                                 u16* __restrict__ houtb) {
    __shared__ u16 As[128 * LDA];
    __shared__ u16 Bs[128 * LDA];
    __shared__ u16 Cs[128 * LDC];
    const int t = threadIdx.x;
    const int lane = t & 63;
    const int w = t >> 6;
    const int wr = w >> 1, wc = w & 1;
    const int row0 = blockIdx.x * 128;
    const int lr = lane & 15;
    const int lk = (lane >> 4) * 8;

    f32x4 acc[4][4];
#pragma unroll
    for (int m = 0; m < 4; ++m)
#pragma unroll
        for (int n = 0; n < 4; ++n) acc[m][n] = (f32x4){0.f, 0.f, 0.f, 0.f};

    for (int kb = 0; kb < 8; ++kb) {
        const u16* xsrc = (kb < 4) ? aggb : hinb;
        const int koff = (kb & 3) * 32;
        // stage A: 128 rows x 32 bf16 (512 chunks of 16 B)
#pragma unroll
        for (int it = 0; it < 2; ++it) {
            int u = it * 256 + t;
            int r = u >> 2, c = (u & 3) * 8;
            bf16x8 v = {};
            if (row0 + r < NNODES)
                v = *(const bf16x8*)(xsrc + (size_t)(row0 + r) * FDIM + koff + c);
            *(bf16x8*)&As[r * LDA + c] = v;
        }
        // stage B: 128 cols x 32 bf16
#pragma unroll
        for (int it = 0; it < 2; ++it) {
            int u = it * 256 + t;
            int r = u >> 2, c = (u & 3) * 8;
            bf16x8 v = *(const bf16x8*)(Wl + (size_t)r * 256 + kb * 32 + c);
            *(bf16x8*)&Bs[r * LDA + c] = v;
        }
        __syncthreads();
        bf16x8 a[4], b[4];
#pragma unroll
        for (int m = 0; m < 4; ++m)
            a[m] = *(const bf16x8*)&As[(wr * 64 + m * 16 + lr) * LDA + lk];
#pragma unroll
        for (int n = 0; n < 4; ++n)
            b[n] = *(const bf16x8*)&Bs[(wc * 64 + n * 16 + lr) * LDA + lk];
#pragma unroll
        for (int m = 0; m < 4; ++m)
#pragma unroll
            for (int n = 0; n < 4; ++n)
                acc[m][n] = __builtin_amdgcn_mfma_f32_16x16x32_bf16(a[m], b[n], acc[m][n], 0, 0, 0);
        __syncthreads();
    }
    // epilogue: bias + relu + bf16, repack via LDS for coalesced stores
#pragma unroll
    for (int m = 0; m < 4; ++m) {
#pragma unroll
        for (int n = 0; n < 4; ++n) {
            int col = wc * 64 + n * 16 + lr;
            float bb = bias[col];
#pragma unroll
            for (int reg = 0; reg < 4; ++reg) {
                int row = wr * 64 + m * 16 + (lane >> 4) * 4 + reg;
                float v = fmaxf(acc[m][n][reg] + bb, 0.f);
                Cs[row * LDC + col] = f2bf(v);
            }
        }
    }
    __syncthreads();
    {
        int r = t >> 1, half = t & 1;
        if (row0 + r < NNODES) {
#pragma unroll
            for (int j = 0; j < 8; ++j) {
                bf16x8 v = *(const bf16x8*)&Cs[r * LDC + half * 64 + j * 8];
                *(bf16x8*)(houtb + (size_t)(row0 + r) * FDIM + half * 64 + j * 8) = v;
            }
        }
    }
}

// ---------------- node-parallel mean pool (bf16 in, fp32 atomics; /count in mlp1) --------

__global__ __launch_bounds__(64) void pool_bf(const u16* __restrict__ h,
                                              const int* __restrict__ batch,
                                              float* __restrict__ z, int layer) {
    const int f2 = threadIdx.x;               // handles features 2*f2, 2*f2+1
    const int n0 = blockIdx.x * POOL_NPB;
    int n1 = n0 + POOL_NPB; if (n1 > NNODES) n1 = NNODES;
    __shared__ int bsh[POOL_NPB];
    for (int n = n0 + f2; n < n1; n += 64) bsh[n - n0] = batch[n];
    __syncthreads();
    float s0 = 0.f, s1 = 0.f;
    int g = bsh[0];
    for (int n = n0; n < n1; ++n) {
        int gn = bsh[n - n0];
        if (gn != g) {
            float* zp = &z[(size_t)g * (NLAYERS * FDIM) + layer * FDIM + 2 * f2];
            atomicAdd(zp, s0); atomicAdd(zp + 1, s1);
            s0 = 0.f; s1 = 0.f; g = gn;
        }
        u32 v = ((const u32*)(h + (size_t)n * FDIM))[f2];
        s0 += bf_lo(v); s1 += bf_hi(v);
    }
    float* zp = &z[(size_t)g * (NLAYERS * FDIM) + layer * FDIM + 2 * f2];
    atomicAdd(zp, s0); atomicAdd(zp + 1, s1);
}

// ---------------- final MLP (mean normalization folded into z load) ----------------

__global__ __launch_bounds__(128) void mlp1(const float* __restrict__ z,
                                            const int* __restrict__ gptr,
                                            const float* __restrict__ Wl1,
                                            const float* __restrict__ bl1,
                                            float* __restrict__ z2) {
    int g = blockIdx.x, j = threadIdx.x;
    __shared__ float zs[NLAYERS * FDIM];
    int cnt = gptr[g + 1] - gptr[g]; if (cnt < 1) cnt = 1;
    float invc = 1.0f / (float)cnt;
    for (int k = j; k < NLAYERS * FDIM; k += 128)
        zs[k] = z[(size_t)g * (NLAYERS * FDIM) + k] * invc;
    __syncthreads();
    float s = bl1[j];
    for (int k = 0; k < NLAYERS * FDIM; ++k) s = fmaf(zs[k], Wl1[(size_t)k * FDIM + j], s);
    z2[(size_t)g * FDIM + j] = fmaxf(s, 0.f);
}

__global__ __launch_bounds__(128) void mlp2(const float* __restrict__ z2,
                                            const float* __restrict__ Wl2,
                                            const float* __restrict__ bl2,
                                            float* __restrict__ out) {
    int g = blockIdx.x, c = threadIdx.x;
    __shared__ float zs[FDIM];
    if (threadIdx.x < FDIM) zs[threadIdx.x] = z2[(size_t)g * FDIM + threadIdx.x];
    __syncthreads();
    if (c < NCLASS) {
        float s = bl2[c];
        for (int k = 0; k < FDIM; ++k) s = fmaf(zs[k], Wl2[(size_t)k * NCLASS + c], s);
        out[(size_t)g * NCLASS + c] = s;
    }
}

// ---------------- launch ----------------

extern "C" void kernel_launch(void* const* d_in, const int* in_sizes, int n_in,
                              void* d_out, int out_size, void* d_ws, size_t ws_size,
                              hipStream_t stream) {
    const float* x       = (const float*)d_in[0];
    const int*   ei      = (const int*)d_in[1];
    const int*   batch   = (const int*)d_in[2];
    const float* W1_rel  = (const float*)d_in[3];
    const float* b1_rel  = (const float*)d_in[4];
    const float* W1_root = (const float*)d_in[5];
    const float* Wc_rel  = (const float*)d_in[6];
    const float* bc_rel  = (const float*)d_in[7];
    const float* Wc_root = (const float*)d_in[8];
    const float* Wl1     = (const float*)d_in[9];
    const float* bl1     = (const float*)d_in[10];
    const float* Wl2     = (const float*)d_in[11];
    const float* bl2     = (const float*)d_in[12];
    float* out = (float*)d_out;

    const int* srcv = ei;            // edge_index[0]
    const int* dstv = ei + NEDGES;   // edge_index[1]

    char* ws = (char*)d_ws;
    size_t off = 0;
    auto alloc = [&](size_t bytes) -> void* {
        void* p = ws + off;
        off = (off + bytes + 255) & ~(size_t)255;
        return p;
    };
    u16* xb      = (u16*)alloc((size_t)NNODES * FDIM * 2);
    u16* hA      = (u16*)alloc((size_t)NNODES * FDIM * 2);
    u16* hB      = (u16*)alloc((size_t)NNODES * FDIM * 2);
    u16* aggb    = (u16*)alloc((size_t)NNODES * FDIM * 2);
    u16* Wcat    = (u16*)alloc((size_t)NLAYERS * 256 * FDIM * 2);
    int* csr     = (int*)alloc((size_t)NEDGES * 4);
    int* row_ptr = (int*)alloc((size_t)(NNODES + 1) * 4);
    int* degcur  = (int*)alloc((size_t)NNODES * 2 * 4);
    int* deg = degcur; int* cursor = degcur + NNODES;
    int* partial = (int*)alloc(4096);
    int* gptr    = (int*)alloc(1024);
    float* z     = (float*)alloc((size_t)NGRAPHS * NLAYERS * FDIM * 4);
    float* z2    = (float*)alloc((size_t)NGRAPHS * FDIM * 4);
    (void)ws_size; (void)in_sizes; (void)n_in; (void)out_size;

    hipMemsetAsync(degcur, 0, (size_t)NNODES * 2 * 4, stream);
    hipMemsetAsync(z, 0, (size_t)NGRAPHS * NLAYERS * FDIM * 4, stream);
    conv_x<<<(NNODES * FDIM / 4 + 255) / 256, 256, 0, stream>>>(x, xb);
    conv_w<<<(NLAYERS * 256 * FDIM + 255) / 256, 256, 0, stream>>>(W1_rel, W1_root, Wc_rel, Wc_root, Wcat);
    graph_ptr_kernel<<<1, 192, 0, stream>>>(batch, gptr);
    deg_kernel<<<(NEDGES + 255) / 256, 256, 0, stream>>>(dstv, deg);
    scan_partial<<<NB_SCAN, 256, 0, stream>>>(deg, partial);
    scan_prefix<<<1, 64, 0, stream>>>(partial);
    scan_final<<<NB_SCAN, 256, 0, stream>>>(deg, partial, row_ptr);
    fill_csr<<<(NEDGES + 255) / 256, 256, 0, stream>>>(srcv, dstv, row_ptr, cursor, csr);

    const int pool_nb = (NNODES + POOL_NPB - 1) / POOL_NPB;
    const u16* hin = xb;
    for (int l = 0; l < NLAYERS; ++l) {
        u16* hout = (l & 1) ? hB : hA;
        const u16* Wl = Wcat + (size_t)l * 256 * FDIM;
        const float* bb = (l == 0) ? b1_rel : bc_rel + (size_t)(l - 1) * FDIM;
        agg_bf<<<(NNODES + 3) / 4, 256, 0, stream>>>(hin, row_ptr, csr, aggb);
        gemm_mfma<<<(NNODES + 127) / 128, 256, 0, stream>>>(aggb, hin, Wl, bb, hout);
        pool_bf<<<pool_nb, 64, 0, stream>>>(hout, batch, z, l);
        hin = hout;
    }
    mlp1<<<NGRAPHS, 128, 0, stream>>>(z, gptr, Wl1, bl1, z2);
    mlp2<<<NGRAPHS, 128, 0, stream>>>(z2, Wl2, bl2, out);
}